// Round 6
// baseline (147.268 us; speedup 1.0000x reference)
//
#include <hip/hip_runtime.h>
#include <math.h>

#define THREADS 256
#define NPTS    8192
#define BATCH   8
#define DIRS    2
#define QPT     8                    // queries per thread (register tile)
#define QPB     (THREADS * QPT)      // 2048 queries per block
#define QBLK    (NPTS / QPB)         // 4 query-blocks
#define DBS     32                   // database splits
#define DBC     (NPTS / DBS)         // 256 db points per block
#define WS_ENTRIES (DIRS * BATCH * NPTS)   // 131072
#define WS_BYTES   (WS_ENTRIES * 4)        // 512 KB

// ---------------- main kernel: partial min over a db chunk ----------------
__global__ __launch_bounds__(THREADS, 8)
void chamfer_min_kernel(const float* __restrict__ pred,
                        const float* __restrict__ target,
                        unsigned* __restrict__ ws)
{
    __shared__ float4 lds[DBC];   // 4 KB: (x, y, z, |t|^2)

    const int bx  = blockIdx.x;
    const int dbs = bx & (DBS - 1);
    const int qb  = (bx >> 5) & (QBLK - 1);
    const int b   = (bx >> 7) & (BATCH - 1);
    const int dir = bx >> 10;

    const float* q  = dir ? target : pred;
    const float* db = dir ? pred   : target;
    const float* dbB = db + ((size_t)b * NPTS + (size_t)dbs * DBC) * 3;

    // stage this block's db chunk into LDS (256 points, 1 iter)
    {
        const int k = threadIdx.x;
        const float* tp = dbB + (size_t)k * 3;
        const float tx = tp[0], ty = tp[1], tz = tp[2];
        lds[k] = make_float4(tx, ty, tz, tx * tx + ty * ty + tz * tz);
    }

    // 8 query points in registers
    float nx[QPT], ny[QPT], nz[QPT], mn[QPT];
    const int q0 = qb * QPB + threadIdx.x;
    #pragma unroll
    for (int k = 0; k < QPT; ++k) {
        const float* qp = q + ((size_t)b * NPTS + q0 + k * THREADS) * 3;
        const float x = qp[0], y = qp[1], z = qp[2];
        nx[k] = -2.0f * x; ny[k] = -2.0f * y; nz[k] = -2.0f * z;
        mn[k] = INFINITY;
    }
    __syncthreads();

    // inner loop: 2 ds_read_b128 broadcasts feed 8 queries x (6 FMA + 1 min3)
    #pragma unroll 4
    for (int j = 0; j < DBC; j += 2) {
        const float4 T0 = lds[j];
        const float4 T1 = lds[j + 1];
        #pragma unroll
        for (int k = 0; k < QPT; ++k) {
            const float e0 = fmaf(nx[k], T0.x,
                             fmaf(ny[k], T0.y,
                             fmaf(nz[k], T0.z, T0.w)));
            const float e1 = fmaf(nx[k], T1.x,
                             fmaf(ny[k], T1.y,
                             fmaf(nz[k], T1.z, T1.w)));
            mn[k] = fminf(mn[k], fminf(e0, e1));   // -> v_min3_f32
        }
    }

    // combine partial mins across the DBS blocks: order-preserving uint key
    #pragma unroll
    for (int k = 0; k < QPT; ++k) {
        const unsigned u   = __float_as_uint(mn[k]);
        const unsigned key = (u >> 31) ? ~u : (u | 0x80000000u);
        atomicMin(&ws[((size_t)dir * BATCH + b) * NPTS + q0 + k * THREADS], key);
    }
}

// ---------------- epilogue: decode, add |p|^2, clamp, mean-reduce ----------------
// each thread: 4 CONSECUTIVE entries -> uint4 ws load + 3x float4 query loads
__global__ __launch_bounds__(THREADS)
void chamfer_finish_kernel(const float* __restrict__ pred,
                           const float* __restrict__ target,
                           const unsigned* __restrict__ ws,
                           float* __restrict__ out,
                           float inv_count)
{
    const int t    = blockIdx.x * THREADS + threadIdx.x;   // 32768 threads
    const int e0   = t * 4;                                // first of 4 entries
    const int dir  = e0 >> 16;                             // 65536 per direction
    const int rem  = e0 & 0xFFFF;
    const int b    = rem >> 13;                            // 8192 per batch
    const int qi   = rem & (NPTS - 1);                     // multiple of 4

    const float* q  = dir ? target : pred;
    const float4* qp = (const float4*)(q + ((size_t)b * NPTS + qi) * 3);
    const float4 v0 = qp[0];   // x0 y0 z0 x1
    const float4 v1 = qp[1];   // y1 z1 x2 y2
    const float4 v2 = qp[2];   // z2 x3 y3 z3

    const uint4 kk = *(const uint4*)(ws + e0);
    float s = 0.0f;
    {
        const unsigned u = (kk.x >> 31) ? (kk.x ^ 0x80000000u) : ~kk.x;
        s += fmaxf(fmaf(v0.x, v0.x, fmaf(v0.y, v0.y, v0.z * v0.z)) + __uint_as_float(u), 0.0f);
    }
    {
        const unsigned u = (kk.y >> 31) ? (kk.y ^ 0x80000000u) : ~kk.y;
        s += fmaxf(fmaf(v0.w, v0.w, fmaf(v1.x, v1.x, v1.y * v1.y)) + __uint_as_float(u), 0.0f);
    }
    {
        const unsigned u = (kk.z >> 31) ? (kk.z ^ 0x80000000u) : ~kk.z;
        s += fmaxf(fmaf(v1.z, v1.z, fmaf(v1.w, v1.w, v2.x * v2.x)) + __uint_as_float(u), 0.0f);
    }
    {
        const unsigned u = (kk.w >> 31) ? (kk.w ^ 0x80000000u) : ~kk.w;
        s += fmaxf(fmaf(v2.y, v2.y, fmaf(v2.z, v2.z, v2.w * v2.w)) + __uint_as_float(u), 0.0f);
    }

    // block reduction
    float v = s;
    #pragma unroll
    for (int off = 32; off > 0; off >>= 1)
        v += __shfl_down(v, off, 64);

    __shared__ float wsum[THREADS / 64];
    const int lane = threadIdx.x & 63;
    const int wid  = threadIdx.x >> 6;
    if (lane == 0) wsum[wid] = v;
    __syncthreads();
    if (threadIdx.x == 0)
        atomicAdd(out, (wsum[0] + wsum[1] + wsum[2] + wsum[3]) * inv_count);
}

// ---------------- fallback (R1 single-kernel) if ws is too small ----------------
__global__ __launch_bounds__(THREADS, 2)
void chamfer_fallback_kernel(const float* __restrict__ pred,
                             const float* __restrict__ target,
                             float* __restrict__ out,
                             float inv_count)
{
    __shared__ float4 lds[2048];
    const float* q  = (blockIdx.y == 0) ? pred   : target;
    const float* db = (blockIdx.y == 0) ? target : pred;
    const int b = blockIdx.x / (NPTS / THREADS);
    const int n = (blockIdx.x % (NPTS / THREADS)) * THREADS + threadIdx.x;
    const float* qp = q + ((size_t)b * NPTS + n) * 3;
    const float px = qp[0], py = qp[1], pz = qp[2];
    const float npx = -2.0f * px, npy = -2.0f * py, npz = -2.0f * pz;
    const float P = px * px + py * py + pz * pz;
    const float* dbB = db + (size_t)b * NPTS * 3;
    float m0 = INFINITY;
    for (int c0 = 0; c0 < NPTS; c0 += 2048) {
        for (int k = 0; k < 2048 / THREADS; ++k) {
            const int j = k * THREADS + threadIdx.x;
            const float* tp = dbB + (size_t)(c0 + j) * 3;
            const float tx = tp[0], ty = tp[1], tz = tp[2];
            lds[j] = make_float4(tx, ty, tz, tx * tx + ty * ty + tz * tz);
        }
        __syncthreads();
        for (int j = 0; j < 2048; ++j) {
            const float4 T = lds[j];
            m0 = fminf(m0, fmaf(npx, T.x, fmaf(npy, T.y, fmaf(npz, T.z, T.w))));
        }
        __syncthreads();
    }
    float v = fmaxf(P + m0, 0.0f);
    #pragma unroll
    for (int off = 32; off > 0; off >>= 1)
        v += __shfl_down(v, off, 64);
    __shared__ float wsum[THREADS / 64];
    if ((threadIdx.x & 63) == 0) wsum[threadIdx.x >> 6] = v;
    __syncthreads();
    if (threadIdx.x == 0)
        atomicAdd(out, (wsum[0] + wsum[1] + wsum[2] + wsum[3]) * inv_count);
}

extern "C" void kernel_launch(void* const* d_in, const int* in_sizes, int n_in,
                              void* d_out, int out_size, void* d_ws, size_t ws_size,
                              hipStream_t stream) {
    const float* pred   = (const float*)d_in[0];
    const float* target = (const float*)d_in[1];
    float* out = (float*)d_out;

    hipMemsetAsync(out, 0, out_size * sizeof(float), stream);

    if (ws_size >= (size_t)WS_BYTES) {
        unsigned* ws = (unsigned*)d_ws;
        // init keys to 0xFFFFFFFF (= +max key, acts as +inf for atomicMin)
        hipMemsetAsync(ws, 0xFF, WS_BYTES, stream);
        dim3 grid(DIRS * BATCH * QBLK * DBS);   // 2048 blocks -> 8 blocks/CU
        chamfer_min_kernel<<<grid, THREADS, 0, stream>>>(pred, target, ws);
        chamfer_finish_kernel<<<WS_ENTRIES / (THREADS * 4), THREADS, 0, stream>>>(
            pred, target, ws, out, 1.0f / (float)(BATCH * NPTS));
    } else {
        dim3 grid(BATCH * (NPTS / THREADS), 2);
        chamfer_fallback_kernel<<<grid, THREADS, 0, stream>>>(
            pred, target, out, 1.0f / (float)(BATCH * NPTS));
    }
}

// Round 9
// 124.162 us; speedup vs baseline: 1.1861x; 1.1861x over previous
//
#include <hip/hip_runtime.h>
#include <math.h>

#define THREADS 256
#define NPTS    8192
#define BATCH   8
#define WS_ENTRIES (2 * BATCH * NPTS)      // 131072 keys
#define WS_BYTES   (WS_ENTRIES * 4)        // 512 KB

typedef __attribute__((ext_vector_type(8)))  short bf16x8;
typedef __attribute__((ext_vector_type(16))) float f32x16;

union FragCast { uint4 u; bf16x8 v; };

__device__ __forceinline__ unsigned short f2bf(float f) {
    unsigned u = __float_as_uint(f);
    unsigned r = (u + 0x7FFFu + ((u >> 16) & 1u)) >> 16;   // RNE
    return (unsigned short)r;
}
__device__ __forceinline__ float bf2f(unsigned short h) {
    return __uint_as_float(((unsigned)h) << 16);
}
#define PK(a, b) (((unsigned)(a)) | (((unsigned)(b)) << 16))
#define BF_ONE 0x3F80u

// ============ MFMA min kernel ============
// grid.x bits: ds(2) | qb(4) | b(3) | dir(1)  -> 1024 blocks, 256 thr (4 waves)
// Each wave: 4 query-subblocks of 32 (B-frags); block sweeps 2048 db points.
__global__ __launch_bounds__(THREADS, 4)
void chamfer_mfma_kernel(const float* __restrict__ pred,
                         const float* __restrict__ target,
                         unsigned* __restrict__ wskeys)
{
    __shared__ short lds[32 * 64 * 8];   // 32 tiles x 64 chunks x 16B = 32 KB

    const int bx  = blockIdx.x;
    const int ds  = bx & 3;
    const int qb  = (bx >> 2) & 15;
    const int b   = (bx >> 6) & 7;
    const int dir = bx >> 9;

    const float* qarr = dir ? target : pred;   // queries (min kept per query)
    const float* darr = dir ? pred   : target; // database (streamed via MFMA A)

    const int tid  = threadIdx.x;
    const int ln   = tid & 63;
    const int w    = tid >> 6;
    const int half = ln >> 5;          // which K-half this lane's frags hold

    // ---- build 4 query B-fragments in registers ----
    bf16x8 bq[4];
    const int qbase = qb * 512 + w * 128;
    #pragma unroll
    for (int nb = 0; nb < 4; ++nb) {
        const int qi = qbase + nb * 32 + (ln & 31);
        const float* qp = qarr + ((size_t)b * NPTS + qi) * 3;
        const float x = qp[0], y = qp[1], z = qp[2];
        const float sq = fmaf(x, x, fmaf(y, y, z * z));
        const float wx = -2.0f * x, wy = -2.0f * y, wz = -2.0f * z;
        const unsigned short wxh = f2bf(wx), wyh = f2bf(wy), wzh = f2bf(wz);
        const unsigned short wxl = f2bf(wx - bf2f(wxh));
        const unsigned short wyl = f2bf(wy - bf2f(wyh));
        const unsigned short wzl = f2bf(wz - bf2f(wzh));
        const unsigned short sh  = f2bf(sq);
        const unsigned short sl  = f2bf(sq - bf2f(sh));
        FragCast fc;
        if (half == 0) {  // k0..7 = [wxh,wyh,wzh, wxh,wyh,wzh, wxl,wyl]
            fc.u = make_uint4(PK(wxh, wyh), PK(wzh, wxh), PK(wyh, wzh), PK(wxl, wyl));
        } else {          // k8..15 = [wzl, wxl,wyl,wzl, 1,1, sqh,sql]
            fc.u = make_uint4(PK(wzl, wxl), PK(wyl, wzl), PK(BF_ONE, BF_ONE), PK(sh, sl));
        }
        bq[nb] = fc.v;
    }

    float mn[4] = {INFINITY, INFINITY, INFINITY, INFINITY};
    const int range0 = ds * 2048;

    for (int chunk = 0; chunk < 2; ++chunk) {
        // ---- stage 1024 db points, encoded, into LDS (lane-linear chunks) ----
        #pragma unroll
        for (int it = 0; it < 4; ++it) {
            const int pl = it * THREADS + tid;          // 0..1023 local point
            const int p  = range0 + chunk * 1024 + pl;  // global db index
            const float* tp = darr + ((size_t)b * NPTS + p) * 3;
            const float x = tp[0], y = tp[1], z = tp[2];
            const float sq = fmaf(x, x, fmaf(y, y, z * z));
            const unsigned short xh = f2bf(x), yh = f2bf(y), zh = f2bf(z);
            const unsigned short xl = f2bf(x - bf2f(xh));
            const unsigned short yl = f2bf(y - bf2f(yh));
            const unsigned short zl = f2bf(z - bf2f(zh));
            const unsigned short sh = f2bf(sq);
            const unsigned short sl = f2bf(sq - bf2f(sh));
            // D row: k0..7 = [xh,yh,zh, xl,yl,zl, xh,yh]; k8..15 = [zh, xl,yl,zl, sqh,sql, 1,1]
            const uint4 h0 = make_uint4(PK(xh, yh), PK(zh, xl), PK(yl, zl), PK(xh, yh));
            const uint4 h1 = make_uint4(PK(zh, xl), PK(yl, zl), PK(sh, sl), PK(BF_ONE, BF_ONE));
            const int j = pl >> 5, c = pl & 31;
            *(uint4*)&lds[(j * 64 + c) * 8]      = h0;   // chunk c   (lanes 0..31)
            *(uint4*)&lds[(j * 64 + c + 32) * 8] = h1;   // chunk c+32 (lanes 32..63)
        }
        __syncthreads();

        // ---- 32 tiles: 1 ds_read_b128 -> 4 MFMA -> 32 v_min3 ----
        #pragma unroll 4
        for (int j = 0; j < 32; ++j) {
            const bf16x8 a = *(const bf16x8*)&lds[(j * 64 + ln) * 8];
            f32x16 z = {};
            f32x16 c0 = __builtin_amdgcn_mfma_f32_32x32x16_bf16(a, bq[0], z, 0, 0, 0);
            f32x16 c1 = __builtin_amdgcn_mfma_f32_32x32x16_bf16(a, bq[1], z, 0, 0, 0);
            f32x16 c2 = __builtin_amdgcn_mfma_f32_32x32x16_bf16(a, bq[2], z, 0, 0, 0);
            f32x16 c3 = __builtin_amdgcn_mfma_f32_32x32x16_bf16(a, bq[3], z, 0, 0, 0);
            #pragma unroll
            for (int i = 0; i < 16; i += 2) {
                mn[0] = fminf(mn[0], fminf(c0[i], c0[i + 1]));
                mn[1] = fminf(mn[1], fminf(c1[i], c1[i + 1]));
                mn[2] = fminf(mn[2], fminf(c2[i], c2[i + 1]));
                mn[3] = fminf(mn[3], fminf(c3[i], c3[i + 1]));
            }
        }
        __syncthreads();
    }

    // ---- cross-half combine + atomicMin merge ----
    const int obase = dir * (BATCH * NPTS) + b * NPTS;
    #pragma unroll
    for (int nb = 0; nb < 4; ++nb) {
        const float o = __shfl_xor(mn[nb], 32, 64);
        const float m = fminf(mn[nb], o);
        if (ln < 32) {
            const unsigned u   = __float_as_uint(m);
            const unsigned key = (u >> 31) ? ~u : (u | 0x80000000u);
            atomicMin(&wskeys[obase + qbase + nb * 32 + ln], key);
        }
    }
}

// ============ epilogue: decode, clamp, mean ============
__global__ __launch_bounds__(THREADS)
void chamfer_finish_kernel(const unsigned* __restrict__ ws,
                           float* __restrict__ out,
                           float inv_count)
{
    const int t = blockIdx.x * THREADS + threadIdx.x;    // 32768 threads
    const uint4 kk = ((const uint4*)ws)[t];
    float s = 0.0f;
    {
        const unsigned u = (kk.x >> 31) ? (kk.x ^ 0x80000000u) : ~kk.x;
        s += fmaxf(__uint_as_float(u), 0.0f);
    }
    {
        const unsigned u = (kk.y >> 31) ? (kk.y ^ 0x80000000u) : ~kk.y;
        s += fmaxf(__uint_as_float(u), 0.0f);
    }
    {
        const unsigned u = (kk.z >> 31) ? (kk.z ^ 0x80000000u) : ~kk.z;
        s += fmaxf(__uint_as_float(u), 0.0f);
    }
    {
        const unsigned u = (kk.w >> 31) ? (kk.w ^ 0x80000000u) : ~kk.w;
        s += fmaxf(__uint_as_float(u), 0.0f);
    }

    float v = s;
    #pragma unroll
    for (int off = 32; off > 0; off >>= 1)
        v += __shfl_down(v, off, 64);

    __shared__ float wsum[THREADS / 64];
    if ((threadIdx.x & 63) == 0) wsum[threadIdx.x >> 6] = v;
    __syncthreads();
    if (threadIdx.x == 0)
        atomicAdd(out, (wsum[0] + wsum[1] + wsum[2] + wsum[3]) * inv_count);
}

// ============ fallback (R1-style) if ws too small ============
__global__ __launch_bounds__(THREADS, 2)
void chamfer_fallback_kernel(const float* __restrict__ pred,
                             const float* __restrict__ target,
                             float* __restrict__ out,
                             float inv_count)
{
    __shared__ float4 lds[2048];
    const float* q  = (blockIdx.y == 0) ? pred   : target;
    const float* db = (blockIdx.y == 0) ? target : pred;
    const int b = blockIdx.x / (NPTS / THREADS);
    const int n = (blockIdx.x % (NPTS / THREADS)) * THREADS + threadIdx.x;
    const float* qp = q + ((size_t)b * NPTS + n) * 3;
    const float px = qp[0], py = qp[1], pz = qp[2];
    const float npx = -2.0f * px, npy = -2.0f * py, npz = -2.0f * pz;
    const float P = px * px + py * py + pz * pz;
    const float* dbB = db + (size_t)b * NPTS * 3;
    float m0 = INFINITY;
    for (int c0 = 0; c0 < NPTS; c0 += 2048) {
        for (int k = 0; k < 2048 / THREADS; ++k) {
            const int j = k * THREADS + threadIdx.x;
            const float* tp = dbB + (size_t)(c0 + j) * 3;
            const float tx = tp[0], ty = tp[1], tz = tp[2];
            lds[j] = make_float4(tx, ty, tz, tx * tx + ty * ty + tz * tz);
        }
        __syncthreads();
        for (int j = 0; j < 2048; ++j) {
            const float4 T = lds[j];
            m0 = fminf(m0, fmaf(npx, T.x, fmaf(npy, T.y, fmaf(npz, T.z, T.w))));
        }
        __syncthreads();
    }
    float v = fmaxf(P + m0, 0.0f);
    #pragma unroll
    for (int off = 32; off > 0; off >>= 1)
        v += __shfl_down(v, off, 64);
    __shared__ float wsum[THREADS / 64];
    if ((threadIdx.x & 63) == 0) wsum[threadIdx.x >> 6] = v;
    __syncthreads();
    if (threadIdx.x == 0)
        atomicAdd(out, (wsum[0] + wsum[1] + wsum[2] + wsum[3]) * inv_count);
}

extern "C" void kernel_launch(void* const* d_in, const int* in_sizes, int n_in,
                              void* d_out, int out_size, void* d_ws, size_t ws_size,
                              hipStream_t stream) {
    const float* pred   = (const float*)d_in[0];
    const float* target = (const float*)d_in[1];
    float* out = (float*)d_out;

    hipMemsetAsync(out, 0, out_size * sizeof(float), stream);

    if (ws_size >= (size_t)WS_BYTES) {
        unsigned* ws = (unsigned*)d_ws;
        hipMemsetAsync(ws, 0xFF, WS_BYTES, stream);   // keys = +inf
        chamfer_mfma_kernel<<<1024, THREADS, 0, stream>>>(pred, target, ws);
        chamfer_finish_kernel<<<WS_ENTRIES / (THREADS * 4), THREADS, 0, stream>>>(
            ws, out, 1.0f / (float)(BATCH * NPTS));
    } else {
        dim3 grid(BATCH * (NPTS / THREADS), 2);
        chamfer_fallback_kernel<<<grid, THREADS, 0, stream>>>(
            pred, target, out, 1.0f / (float)(BATCH * NPTS));
    }
}

// Round 10
// 99.532 us; speedup vs baseline: 1.4796x; 1.2475x over previous
//
#include <hip/hip_runtime.h>
#include <math.h>

#define THREADS  256
#define NPTS     8192
#define BATCH    8
#define ENTRIES  (2 * BATCH * NPTS)        // 131072 per-query slots
#define WS2_BYTES ((size_t)2 * ENTRIES * 4) // 1 MB  (2 ds-planes, plain float)
#define WS_BYTES  ((size_t)ENTRIES * 4)     // 512 KB (atomic-key tier)

typedef __attribute__((ext_vector_type(8)))  short bf16x8;
typedef __attribute__((ext_vector_type(16))) float f32x16;

union FragCast { uint4 u; bf16x8 v; };

__device__ __forceinline__ unsigned short f2bf(float f) {
    unsigned u = __float_as_uint(f);
    unsigned r = (u + 0x7FFFu + ((u >> 16) & 1u)) >> 16;   // RNE
    return (unsigned short)r;
}
__device__ __forceinline__ float bf2f(unsigned short h) {
    return __uint_as_float(((unsigned)h) << 16);
}
#define PK(a, b) (((unsigned)(a)) | (((unsigned)(b)) << 16))
#define BF_ONE 0x3F80u

// ================= tier-1 min kernel (no atomics) =================
// grid.x bits: ds(1) | qb(5) | b(3) | dir(1) -> 1024 blocks, 4 waves each.
// Wave: 2 query-frags (64 queries); block sweeps 4096 db points (4 chunks).
// Per MFMA result: 16 independent running-min updates (no min3 tree in loop).
__global__ __launch_bounds__(THREADS, 4)
void chamfer_mfma2_kernel(const float* __restrict__ pred,
                          const float* __restrict__ target,
                          float* __restrict__ ws2)
{
    __shared__ short lds[32 * 64 * 8];   // 32 KB

    const int bx  = blockIdx.x;
    const int ds  = bx & 1;
    const int qb  = (bx >> 1) & 31;
    const int b   = (bx >> 6) & 7;
    const int dir = bx >> 9;

    const float* qarr = dir ? target : pred;
    const float* darr = dir ? pred   : target;

    const int tid  = threadIdx.x;
    const int ln   = tid & 63;
    const int w    = tid >> 6;
    const int half = ln >> 5;

    // ---- 2 query B-fragments ----
    bf16x8 bq0, bq1;
    const int qbase = qb * 256 + w * 64;
    #pragma unroll
    for (int nb = 0; nb < 2; ++nb) {
        const int qi = qbase + nb * 32 + (ln & 31);
        const float* qp = qarr + ((size_t)b * NPTS + qi) * 3;
        const float x = qp[0], y = qp[1], z = qp[2];
        const float sq = fmaf(x, x, fmaf(y, y, z * z));
        const float wx = -2.0f * x, wy = -2.0f * y, wz = -2.0f * z;
        const unsigned short wxh = f2bf(wx), wyh = f2bf(wy), wzh = f2bf(wz);
        const unsigned short wxl = f2bf(wx - bf2f(wxh));
        const unsigned short wyl = f2bf(wy - bf2f(wyh));
        const unsigned short wzl = f2bf(wz - bf2f(wzh));
        const unsigned short sh  = f2bf(sq);
        const unsigned short sl  = f2bf(sq - bf2f(sh));
        FragCast fc;
        if (half == 0) {
            fc.u = make_uint4(PK(wxh, wyh), PK(wzh, wxh), PK(wyh, wzh), PK(wxl, wyl));
        } else {
            fc.u = make_uint4(PK(wzl, wxl), PK(wyl, wzl), PK(BF_ONE, BF_ONE), PK(sh, sl));
        }
        if (nb == 0) bq0 = fc.v; else bq1 = fc.v;
    }

    const f32x16 zacc = {};        // hoisted zero C operand
    f32x16 m0, m1;                 // 16 running mins per frag
    #pragma unroll
    for (int i = 0; i < 16; ++i) { m0[i] = INFINITY; m1[i] = INFINITY; }

    const int range0 = ds * 4096;

    for (int chunk = 0; chunk < 4; ++chunk) {
        // ---- stage 1024 encoded db points ----
        #pragma unroll
        for (int it = 0; it < 4; ++it) {
            const int pl = it * THREADS + tid;
            const int p  = range0 + chunk * 1024 + pl;
            const float* tp = darr + ((size_t)b * NPTS + p) * 3;
            const float x = tp[0], y = tp[1], z = tp[2];
            const float sq = fmaf(x, x, fmaf(y, y, z * z));
            const unsigned short xh = f2bf(x), yh = f2bf(y), zh = f2bf(z);
            const unsigned short xl = f2bf(x - bf2f(xh));
            const unsigned short yl = f2bf(y - bf2f(yh));
            const unsigned short zl = f2bf(z - bf2f(zh));
            const unsigned short sh = f2bf(sq);
            const unsigned short sl = f2bf(sq - bf2f(sh));
            const uint4 h0 = make_uint4(PK(xh, yh), PK(zh, xl), PK(yl, zl), PK(xh, yh));
            const uint4 h1 = make_uint4(PK(zh, xl), PK(yl, zl), PK(sh, sl), PK(BF_ONE, BF_ONE));
            const int j = pl >> 5, c = pl & 31;
            *(uint4*)&lds[(j * 64 + c) * 8]      = h0;
            *(uint4*)&lds[(j * 64 + c + 32) * 8] = h1;
        }
        __syncthreads();

        // ---- 32 tiles: 1 ds_read_b128 -> 2 MFMA -> 32 independent v_min ----
        #pragma unroll 2
        for (int j = 0; j < 32; ++j) {
            const bf16x8 a = *(const bf16x8*)&lds[(j * 64 + ln) * 8];
            const f32x16 c0 = __builtin_amdgcn_mfma_f32_32x32x16_bf16(a, bq0, zacc, 0, 0, 0);
            const f32x16 c1 = __builtin_amdgcn_mfma_f32_32x32x16_bf16(a, bq1, zacc, 0, 0, 0);
            #pragma unroll
            for (int i = 0; i < 16; ++i) m0[i] = fminf(m0[i], c0[i]);
            #pragma unroll
            for (int i = 0; i < 16; ++i) m1[i] = fminf(m1[i], c1[i]);
        }
        __syncthreads();
    }

    // ---- fold 16 -> 1 (once), cross-half, plain store to ds-plane ----
    float r0, r1;
    {
        float a0 = fminf(fminf(m0[0], m0[1]), fminf(m0[2], m0[3]));
        float a1 = fminf(fminf(m0[4], m0[5]), fminf(m0[6], m0[7]));
        float a2 = fminf(fminf(m0[8], m0[9]), fminf(m0[10], m0[11]));
        float a3 = fminf(fminf(m0[12], m0[13]), fminf(m0[14], m0[15]));
        r0 = fminf(fminf(a0, a1), fminf(a2, a3));
        float b0 = fminf(fminf(m1[0], m1[1]), fminf(m1[2], m1[3]));
        float b1 = fminf(fminf(m1[4], m1[5]), fminf(m1[6], m1[7]));
        float b2 = fminf(fminf(m1[8], m1[9]), fminf(m1[10], m1[11]));
        float b3 = fminf(fminf(m1[12], m1[13]), fminf(m1[14], m1[15]));
        r1 = fminf(fminf(b0, b1), fminf(b2, b3));
    }
    r0 = fminf(r0, __shfl_xor(r0, 32, 64));
    r1 = fminf(r1, __shfl_xor(r1, 32, 64));
    if (ln < 32) {
        const int base = ds * ENTRIES + dir * (BATCH * NPTS) + b * NPTS + qbase;
        ws2[base + ln]      = r0;
        ws2[base + 32 + ln] = r1;
    }
}

// ---- tier-1 finish: single block, min 2 planes, clamp, sum, direct write ----
__global__ __launch_bounds__(1024)
void chamfer_finish2_kernel(const float* __restrict__ ws2,
                            float* __restrict__ out,
                            float inv_count)
{
    const float4* p0 = (const float4*)ws2;
    const float4* p1 = (const float4*)(ws2 + ENTRIES);
    float s = 0.0f;
    #pragma unroll 4
    for (int t = threadIdx.x; t < ENTRIES / 4; t += 1024) {
        const float4 a = p0[t];
        const float4 c = p1[t];
        s += fmaxf(fminf(a.x, c.x), 0.0f) + fmaxf(fminf(a.y, c.y), 0.0f)
           + fmaxf(fminf(a.z, c.z), 0.0f) + fmaxf(fminf(a.w, c.w), 0.0f);
    }
    float v = s;
    #pragma unroll
    for (int off = 32; off > 0; off >>= 1)
        v += __shfl_down(v, off, 64);

    __shared__ float wsum[16];
    if ((threadIdx.x & 63) == 0) wsum[threadIdx.x >> 6] = v;
    __syncthreads();
    if (threadIdx.x == 0) {
        float t = 0.0f;
        #pragma unroll
        for (int i = 0; i < 16; ++i) t += wsum[i];
        out[0] = t * inv_count;
    }
}

// ================= tier-2: R9 atomic-key kernels (ws in [512K,1M)) =================
__global__ __launch_bounds__(THREADS, 4)
void chamfer_mfma_kernel(const float* __restrict__ pred,
                         const float* __restrict__ target,
                         unsigned* __restrict__ wskeys)
{
    __shared__ short lds[32 * 64 * 8];
    const int bx  = blockIdx.x;
    const int ds  = bx & 3;
    const int qb  = (bx >> 2) & 15;
    const int b   = (bx >> 6) & 7;
    const int dir = bx >> 9;
    const float* qarr = dir ? target : pred;
    const float* darr = dir ? pred   : target;
    const int tid  = threadIdx.x;
    const int ln   = tid & 63;
    const int w    = tid >> 6;
    const int half = ln >> 5;

    bf16x8 bq[4];
    const int qbase = qb * 512 + w * 128;
    #pragma unroll
    for (int nb = 0; nb < 4; ++nb) {
        const int qi = qbase + nb * 32 + (ln & 31);
        const float* qp = qarr + ((size_t)b * NPTS + qi) * 3;
        const float x = qp[0], y = qp[1], z = qp[2];
        const float sq = fmaf(x, x, fmaf(y, y, z * z));
        const float wx = -2.0f * x, wy = -2.0f * y, wz = -2.0f * z;
        const unsigned short wxh = f2bf(wx), wyh = f2bf(wy), wzh = f2bf(wz);
        const unsigned short wxl = f2bf(wx - bf2f(wxh));
        const unsigned short wyl = f2bf(wy - bf2f(wyh));
        const unsigned short wzl = f2bf(wz - bf2f(wzh));
        const unsigned short sh  = f2bf(sq);
        const unsigned short sl  = f2bf(sq - bf2f(sh));
        FragCast fc;
        if (half == 0) fc.u = make_uint4(PK(wxh, wyh), PK(wzh, wxh), PK(wyh, wzh), PK(wxl, wyl));
        else           fc.u = make_uint4(PK(wzl, wxl), PK(wyl, wzl), PK(BF_ONE, BF_ONE), PK(sh, sl));
        bq[nb] = fc.v;
    }

    float mn[4] = {INFINITY, INFINITY, INFINITY, INFINITY};
    const int range0 = ds * 2048;
    for (int chunk = 0; chunk < 2; ++chunk) {
        #pragma unroll
        for (int it = 0; it < 4; ++it) {
            const int pl = it * THREADS + tid;
            const int p  = range0 + chunk * 1024 + pl;
            const float* tp = darr + ((size_t)b * NPTS + p) * 3;
            const float x = tp[0], y = tp[1], z = tp[2];
            const float sq = fmaf(x, x, fmaf(y, y, z * z));
            const unsigned short xh = f2bf(x), yh = f2bf(y), zh = f2bf(z);
            const unsigned short xl = f2bf(x - bf2f(xh));
            const unsigned short yl = f2bf(y - bf2f(yh));
            const unsigned short zl = f2bf(z - bf2f(zh));
            const unsigned short sh = f2bf(sq);
            const unsigned short sl = f2bf(sq - bf2f(sh));
            const uint4 h0 = make_uint4(PK(xh, yh), PK(zh, xl), PK(yl, zl), PK(xh, yh));
            const uint4 h1 = make_uint4(PK(zh, xl), PK(yl, zl), PK(sh, sl), PK(BF_ONE, BF_ONE));
            const int j = pl >> 5, c = pl & 31;
            *(uint4*)&lds[(j * 64 + c) * 8]      = h0;
            *(uint4*)&lds[(j * 64 + c + 32) * 8] = h1;
        }
        __syncthreads();
        #pragma unroll 4
        for (int j = 0; j < 32; ++j) {
            const bf16x8 a = *(const bf16x8*)&lds[(j * 64 + ln) * 8];
            f32x16 z = {};
            f32x16 c0 = __builtin_amdgcn_mfma_f32_32x32x16_bf16(a, bq[0], z, 0, 0, 0);
            f32x16 c1 = __builtin_amdgcn_mfma_f32_32x32x16_bf16(a, bq[1], z, 0, 0, 0);
            f32x16 c2 = __builtin_amdgcn_mfma_f32_32x32x16_bf16(a, bq[2], z, 0, 0, 0);
            f32x16 c3 = __builtin_amdgcn_mfma_f32_32x32x16_bf16(a, bq[3], z, 0, 0, 0);
            #pragma unroll
            for (int i = 0; i < 16; i += 2) {
                mn[0] = fminf(mn[0], fminf(c0[i], c0[i + 1]));
                mn[1] = fminf(mn[1], fminf(c1[i], c1[i + 1]));
                mn[2] = fminf(mn[2], fminf(c2[i], c2[i + 1]));
                mn[3] = fminf(mn[3], fminf(c3[i], c3[i + 1]));
            }
        }
        __syncthreads();
    }
    const int obase = dir * (BATCH * NPTS) + b * NPTS;
    #pragma unroll
    for (int nb = 0; nb < 4; ++nb) {
        const float o = __shfl_xor(mn[nb], 32, 64);
        const float m = fminf(mn[nb], o);
        if (ln < 32) {
            const unsigned u   = __float_as_uint(m);
            const unsigned key = (u >> 31) ? ~u : (u | 0x80000000u);
            atomicMin(&wskeys[obase + qbase + nb * 32 + ln], key);
        }
    }
}

__global__ __launch_bounds__(THREADS)
void chamfer_finish_kernel(const unsigned* __restrict__ ws,
                           float* __restrict__ out,
                           float inv_count)
{
    const int t = blockIdx.x * THREADS + threadIdx.x;
    const uint4 kk = ((const uint4*)ws)[t];
    float s = 0.0f;
    { const unsigned u = (kk.x >> 31) ? (kk.x ^ 0x80000000u) : ~kk.x; s += fmaxf(__uint_as_float(u), 0.0f); }
    { const unsigned u = (kk.y >> 31) ? (kk.y ^ 0x80000000u) : ~kk.y; s += fmaxf(__uint_as_float(u), 0.0f); }
    { const unsigned u = (kk.z >> 31) ? (kk.z ^ 0x80000000u) : ~kk.z; s += fmaxf(__uint_as_float(u), 0.0f); }
    { const unsigned u = (kk.w >> 31) ? (kk.w ^ 0x80000000u) : ~kk.w; s += fmaxf(__uint_as_float(u), 0.0f); }
    float v = s;
    #pragma unroll
    for (int off = 32; off > 0; off >>= 1)
        v += __shfl_down(v, off, 64);
    __shared__ float wsum[THREADS / 64];
    if ((threadIdx.x & 63) == 0) wsum[threadIdx.x >> 6] = v;
    __syncthreads();
    if (threadIdx.x == 0)
        atomicAdd(out, (wsum[0] + wsum[1] + wsum[2] + wsum[3]) * inv_count);
}

// ================= tier-3 fallback (no usable ws) =================
__global__ __launch_bounds__(THREADS, 2)
void chamfer_fallback_kernel(const float* __restrict__ pred,
                             const float* __restrict__ target,
                             float* __restrict__ out,
                             float inv_count)
{
    __shared__ float4 lds[2048];
    const float* q  = (blockIdx.y == 0) ? pred   : target;
    const float* db = (blockIdx.y == 0) ? target : pred;
    const int b = blockIdx.x / (NPTS / THREADS);
    const int n = (blockIdx.x % (NPTS / THREADS)) * THREADS + threadIdx.x;
    const float* qp = q + ((size_t)b * NPTS + n) * 3;
    const float px = qp[0], py = qp[1], pz = qp[2];
    const float npx = -2.0f * px, npy = -2.0f * py, npz = -2.0f * pz;
    const float P = px * px + py * py + pz * pz;
    const float* dbB = db + (size_t)b * NPTS * 3;
    float m0 = INFINITY;
    for (int c0 = 0; c0 < NPTS; c0 += 2048) {
        for (int k = 0; k < 2048 / THREADS; ++k) {
            const int j = k * THREADS + threadIdx.x;
            const float* tp = dbB + (size_t)(c0 + j) * 3;
            const float tx = tp[0], ty = tp[1], tz = tp[2];
            lds[j] = make_float4(tx, ty, tz, tx * tx + ty * ty + tz * tz);
        }
        __syncthreads();
        for (int j = 0; j < 2048; ++j) {
            const float4 T = lds[j];
            m0 = fminf(m0, fmaf(npx, T.x, fmaf(npy, T.y, fmaf(npz, T.z, T.w))));
        }
        __syncthreads();
    }
    float v = fmaxf(P + m0, 0.0f);
    #pragma unroll
    for (int off = 32; off > 0; off >>= 1)
        v += __shfl_down(v, off, 64);
    __shared__ float wsum[THREADS / 64];
    if ((threadIdx.x & 63) == 0) wsum[threadIdx.x >> 6] = v;
    __syncthreads();
    if (threadIdx.x == 0)
        atomicAdd(out, (wsum[0] + wsum[1] + wsum[2] + wsum[3]) * inv_count);
}

extern "C" void kernel_launch(void* const* d_in, const int* in_sizes, int n_in,
                              void* d_out, int out_size, void* d_ws, size_t ws_size,
                              hipStream_t stream) {
    const float* pred   = (const float*)d_in[0];
    const float* target = (const float*)d_in[1];
    float* out = (float*)d_out;

    if (ws_size >= WS2_BYTES) {
        // tier 1: no memsets, no atomics, 2 launches total
        float* ws2 = (float*)d_ws;
        chamfer_mfma2_kernel<<<1024, THREADS, 0, stream>>>(pred, target, ws2);
        chamfer_finish2_kernel<<<1, 1024, 0, stream>>>(ws2, out, 1.0f / (float)(BATCH * NPTS));
    } else if (ws_size >= WS_BYTES) {
        hipMemsetAsync(out, 0, out_size * sizeof(float), stream);
        unsigned* ws = (unsigned*)d_ws;
        hipMemsetAsync(ws, 0xFF, WS_BYTES, stream);
        chamfer_mfma_kernel<<<1024, THREADS, 0, stream>>>(pred, target, ws);
        chamfer_finish_kernel<<<ENTRIES / (THREADS * 4), THREADS, 0, stream>>>(
            ws, out, 1.0f / (float)(BATCH * NPTS));
    } else {
        hipMemsetAsync(out, 0, out_size * sizeof(float), stream);
        dim3 grid(BATCH * (NPTS / THREADS), 2);
        chamfer_fallback_kernel<<<grid, THREADS, 0, stream>>>(
            pred, target, out, 1.0f / (float)(BATCH * NPTS));
    }
}

// Round 11
// 96.924 us; speedup vs baseline: 1.5194x; 1.0269x over previous
//
#include <hip/hip_runtime.h>
#include <math.h>

#define THREADS  256
#define NPTS     8192
#define BATCH    8
#define ENTRIES  (2 * BATCH * NPTS)             // 131072 per-query slots
#define ENC_U4   (2 * BATCH * NPTS / 1024 * 2048) // 262144 uint4 = 4 MB
#define ENC_BYTES ((size_t)ENC_U4 * 16)
#define MINS_BYTES ((size_t)2 * ENTRIES * 4)    // 1 MB (2 ds planes)
#define WS1_BYTES (ENC_BYTES + MINS_BYTES)      // 5 MB tier-1
#define WS_BYTES  ((size_t)ENTRIES * 4)         // 512 KB tier-2

typedef __attribute__((ext_vector_type(8)))  short bf16x8;
typedef __attribute__((ext_vector_type(16))) float f32x16;

union FragCast { uint4 u; bf16x8 v; };

__device__ __forceinline__ unsigned short f2bf(float f) {
    unsigned u = __float_as_uint(f);
    unsigned r = (u + 0x7FFFu + ((u >> 16) & 1u)) >> 16;   // RNE
    return (unsigned short)r;
}
__device__ __forceinline__ float bf2f(unsigned short h) {
    return __uint_as_float(((unsigned)h) << 16);
}
#define PK(a, b) (((unsigned)(a)) | (((unsigned)(b)) << 16))
#define BF_ONE 0x3F80u

__device__ __forceinline__ void async_copy16(void* lds_dst, const void* g_src) {
    __builtin_amdgcn_global_load_lds(
        (const __attribute__((address_space(1))) unsigned*)g_src,
        (__attribute__((address_space(3))) unsigned*)lds_dst,
        16, 0, 0);
}

// ---------- encode a point (x,y,z) into the two 16B K-half rows ----------
__device__ __forceinline__ void encode_db_point(float x, float y, float z,
                                                uint4& h0, uint4& h1) {
    const float sq = fmaf(x, x, fmaf(y, y, z * z));
    const unsigned short xh = f2bf(x), yh = f2bf(y), zh = f2bf(z);
    const unsigned short xl = f2bf(x - bf2f(xh));
    const unsigned short yl = f2bf(y - bf2f(yh));
    const unsigned short zl = f2bf(z - bf2f(zh));
    const unsigned short sh = f2bf(sq);
    const unsigned short sl = f2bf(sq - bf2f(sh));
    h0 = make_uint4(PK(xh, yh), PK(zh, xl), PK(yl, zl), PK(xh, yh));
    h1 = make_uint4(PK(zh, xl), PK(yl, zl), PK(sh, sl), PK(BF_ONE, BF_ONE));
}

// ================= tier-1a: pre-encode both arrays into LDS-image layout =================
// enc[arr][b][chunk] = 2048 uint4; within chunk: point pl -> j=pl>>5, c=pl&31,
// h0 at (j*64+c), h1 at (j*64+c+32).   arr0 = pred, arr1 = target.
__global__ __launch_bounds__(THREADS)
void chamfer_encode_kernel(const float* __restrict__ pred,
                           const float* __restrict__ target,
                           uint4* __restrict__ enc)
{
    const int t   = blockIdx.x * THREADS + threadIdx.x;   // 0..131071
    const int arr = t >> 16;
    const int rem = t & 0xFFFF;
    const int b   = rem >> 13;
    const int p   = rem & (NPTS - 1);
    const float* src = (arr ? target : pred) + ((size_t)b * NPTS + p) * 3;
    uint4 h0, h1;
    encode_db_point(src[0], src[1], src[2], h0, h1);
    const int chunk = p >> 10, pl = p & 1023;
    const int j = pl >> 5, c = pl & 31;
    uint4* base = enc + ((size_t)((arr * BATCH + b) * 8 + chunk)) * 2048;
    base[j * 64 + c]      = h0;
    base[j * 64 + c + 32] = h1;
}

// ================= tier-1b: MFMA min kernel =================
// grid bits: ds(1) | qb(5) | b(3) | dir(1) -> 1024 blocks, 4 waves.
// Stage pre-encoded chunks via global_load_lds; min3-pair across 2 db tiles.
__global__ __launch_bounds__(THREADS, 4)
void chamfer_mfma3_kernel(const float* __restrict__ pred,
                          const float* __restrict__ target,
                          const uint4* __restrict__ enc,
                          float* __restrict__ mins)
{
    __shared__ uint4 lds[2048];   // 32 KB = one 1024-point chunk image

    const int bx  = blockIdx.x;
    const int ds  = bx & 1;
    const int qb  = (bx >> 1) & 31;
    const int b   = (bx >> 6) & 7;
    const int dir = bx >> 9;

    const float* qarr = dir ? target : pred;
    const int arr_db  = dir ^ 1;               // db array index in enc

    const int tid  = threadIdx.x;
    const int ln   = tid & 63;
    const int w    = tid >> 6;
    const int half = ln >> 5;

    // ---- 2 query B-fragments (in-register encode) ----
    bf16x8 bq0, bq1;
    const int qbase = qb * 256 + w * 64;
    #pragma unroll
    for (int nb = 0; nb < 2; ++nb) {
        const int qi = qbase + nb * 32 + (ln & 31);
        const float* qp = qarr + ((size_t)b * NPTS + qi) * 3;
        const float x = qp[0], y = qp[1], z = qp[2];
        const float sq = fmaf(x, x, fmaf(y, y, z * z));
        const float wx = -2.0f * x, wy = -2.0f * y, wz = -2.0f * z;
        const unsigned short wxh = f2bf(wx), wyh = f2bf(wy), wzh = f2bf(wz);
        const unsigned short wxl = f2bf(wx - bf2f(wxh));
        const unsigned short wyl = f2bf(wy - bf2f(wyh));
        const unsigned short wzl = f2bf(wz - bf2f(wzh));
        const unsigned short sh  = f2bf(sq);
        const unsigned short sl  = f2bf(sq - bf2f(sh));
        FragCast fc;
        if (half == 0) fc.u = make_uint4(PK(wxh, wyh), PK(wzh, wxh), PK(wyh, wzh), PK(wxl, wyl));
        else           fc.u = make_uint4(PK(wzl, wxl), PK(wyl, wzl), PK(BF_ONE, BF_ONE), PK(sh, sl));
        if (nb == 0) bq0 = fc.v; else bq1 = fc.v;
    }

    const f32x16 zacc = {};
    f32x16 m0, m1;
    #pragma unroll
    for (int i = 0; i < 16; ++i) { m0[i] = INFINITY; m1[i] = INFINITY; }

    for (int chunk = 0; chunk < 4; ++chunk) {
        // ---- async stage: 8x 1KB global_load_lds per wave ----
        const uint4* gch = enc + ((size_t)((arr_db * BATCH + b) * 8 + ds * 4 + chunk)) * 2048;
        #pragma unroll
        for (int k = 0; k < 8; ++k) {
            const int blk = w * 8 + k;                     // 0..31
            async_copy16(&lds[blk * 64], gch + blk * 64 + ln);
        }
        __syncthreads();   // compiler drains vmcnt before barrier

        // ---- 16 tile-pairs: 2 ds_read_b128 -> 4 MFMA -> 32 min3 ----
        #pragma unroll 2
        for (int j = 0; j < 32; j += 2) {
            FragCast a0, a1;
            a0.u = lds[j * 64 + ln];
            a1.u = lds[(j + 1) * 64 + ln];
            const f32x16 c00 = __builtin_amdgcn_mfma_f32_32x32x16_bf16(a0.v, bq0, zacc, 0, 0, 0);
            const f32x16 c01 = __builtin_amdgcn_mfma_f32_32x32x16_bf16(a1.v, bq0, zacc, 0, 0, 0);
            #pragma unroll
            for (int i = 0; i < 16; ++i)
                m0[i] = fminf(fminf(m0[i], c00[i]), c01[i]);   // v_min3_f32
            const f32x16 c10 = __builtin_amdgcn_mfma_f32_32x32x16_bf16(a0.v, bq1, zacc, 0, 0, 0);
            const f32x16 c11 = __builtin_amdgcn_mfma_f32_32x32x16_bf16(a1.v, bq1, zacc, 0, 0, 0);
            #pragma unroll
            for (int i = 0; i < 16; ++i)
                m1[i] = fminf(fminf(m1[i], c10[i]), c11[i]);
        }
        __syncthreads();
    }

    // ---- fold 16 -> 1, cross-half, plain store to ds-plane ----
    float r0, r1;
    {
        float a0 = fminf(fminf(m0[0], m0[1]), fminf(m0[2], m0[3]));
        float a1 = fminf(fminf(m0[4], m0[5]), fminf(m0[6], m0[7]));
        float a2 = fminf(fminf(m0[8], m0[9]), fminf(m0[10], m0[11]));
        float a3 = fminf(fminf(m0[12], m0[13]), fminf(m0[14], m0[15]));
        r0 = fminf(fminf(a0, a1), fminf(a2, a3));
        float b0 = fminf(fminf(m1[0], m1[1]), fminf(m1[2], m1[3]));
        float b1 = fminf(fminf(m1[4], m1[5]), fminf(m1[6], m1[7]));
        float b2 = fminf(fminf(m1[8], m1[9]), fminf(m1[10], m1[11]));
        float b3 = fminf(fminf(m1[12], m1[13]), fminf(m1[14], m1[15]));
        r1 = fminf(fminf(b0, b1), fminf(b2, b3));
    }
    r0 = fminf(r0, __shfl_xor(r0, 32, 64));
    r1 = fminf(r1, __shfl_xor(r1, 32, 64));
    if (ln < 32) {
        const int base = ds * ENTRIES + dir * (BATCH * NPTS) + b * NPTS + qbase;
        mins[base + ln]      = r0;
        mins[base + 32 + ln] = r1;
    }
}

// ---- tier-1c finish: 64 blocks, min 2 planes, clamp, sum, atomicAdd ----
__global__ __launch_bounds__(THREADS)
void chamfer_finish3_kernel(const float* __restrict__ mins,
                            float* __restrict__ out,
                            float inv_count)
{
    const int t = blockIdx.x * THREADS + threadIdx.x;     // 0..16383
    const float4* p0 = (const float4*)mins;
    const float4* p1 = (const float4*)(mins + ENTRIES);
    float s = 0.0f;
    #pragma unroll
    for (int k = 0; k < 2; ++k) {
        const int i4 = t * 2 + k;
        const float4 a = p0[i4];
        const float4 c = p1[i4];
        s += fmaxf(fminf(a.x, c.x), 0.0f) + fmaxf(fminf(a.y, c.y), 0.0f)
           + fmaxf(fminf(a.z, c.z), 0.0f) + fmaxf(fminf(a.w, c.w), 0.0f);
    }
    float v = s;
    #pragma unroll
    for (int off = 32; off > 0; off >>= 1)
        v += __shfl_down(v, off, 64);
    __shared__ float wsum[THREADS / 64];
    if ((threadIdx.x & 63) == 0) wsum[threadIdx.x >> 6] = v;
    __syncthreads();
    if (threadIdx.x == 0)
        atomicAdd(out, (wsum[0] + wsum[1] + wsum[2] + wsum[3]) * inv_count);
}

// ================= tier-2: R9 atomic-key kernels (ws in [512K, 5M)) =================
__global__ __launch_bounds__(THREADS, 4)
void chamfer_mfma_kernel(const float* __restrict__ pred,
                         const float* __restrict__ target,
                         unsigned* __restrict__ wskeys)
{
    __shared__ short lds[32 * 64 * 8];
    const int bx  = blockIdx.x;
    const int ds  = bx & 3;
    const int qb  = (bx >> 2) & 15;
    const int b   = (bx >> 6) & 7;
    const int dir = bx >> 9;
    const float* qarr = dir ? target : pred;
    const float* darr = dir ? pred   : target;
    const int tid  = threadIdx.x;
    const int ln   = tid & 63;
    const int w    = tid >> 6;
    const int half = ln >> 5;

    bf16x8 bq[4];
    const int qbase = qb * 512 + w * 128;
    #pragma unroll
    for (int nb = 0; nb < 4; ++nb) {
        const int qi = qbase + nb * 32 + (ln & 31);
        const float* qp = qarr + ((size_t)b * NPTS + qi) * 3;
        const float x = qp[0], y = qp[1], z = qp[2];
        const float sq = fmaf(x, x, fmaf(y, y, z * z));
        const float wx = -2.0f * x, wy = -2.0f * y, wz = -2.0f * z;
        const unsigned short wxh = f2bf(wx), wyh = f2bf(wy), wzh = f2bf(wz);
        const unsigned short wxl = f2bf(wx - bf2f(wxh));
        const unsigned short wyl = f2bf(wy - bf2f(wyh));
        const unsigned short wzl = f2bf(wz - bf2f(wzh));
        const unsigned short sh  = f2bf(sq);
        const unsigned short sl  = f2bf(sq - bf2f(sh));
        FragCast fc;
        if (half == 0) fc.u = make_uint4(PK(wxh, wyh), PK(wzh, wxh), PK(wyh, wzh), PK(wxl, wyl));
        else           fc.u = make_uint4(PK(wzl, wxl), PK(wyl, wzl), PK(BF_ONE, BF_ONE), PK(sh, sl));
        bq[nb] = fc.v;
    }

    float mn[4] = {INFINITY, INFINITY, INFINITY, INFINITY};
    const int range0 = ds * 2048;
    for (int chunk = 0; chunk < 2; ++chunk) {
        #pragma unroll
        for (int it = 0; it < 4; ++it) {
            const int pl = it * THREADS + tid;
            const int p  = range0 + chunk * 1024 + pl;
            const float* tp = darr + ((size_t)b * NPTS + p) * 3;
            uint4 h0, h1;
            encode_db_point(tp[0], tp[1], tp[2], h0, h1);
            const int j = pl >> 5, c = pl & 31;
            *(uint4*)&lds[(j * 64 + c) * 8]      = h0;
            *(uint4*)&lds[(j * 64 + c + 32) * 8] = h1;
        }
        __syncthreads();
        #pragma unroll 4
        for (int j = 0; j < 32; ++j) {
            const bf16x8 a = *(const bf16x8*)&lds[(j * 64 + ln) * 8];
            f32x16 z = {};
            f32x16 c0 = __builtin_amdgcn_mfma_f32_32x32x16_bf16(a, bq[0], z, 0, 0, 0);
            f32x16 c1 = __builtin_amdgcn_mfma_f32_32x32x16_bf16(a, bq[1], z, 0, 0, 0);
            f32x16 c2 = __builtin_amdgcn_mfma_f32_32x32x16_bf16(a, bq[2], z, 0, 0, 0);
            f32x16 c3 = __builtin_amdgcn_mfma_f32_32x32x16_bf16(a, bq[3], z, 0, 0, 0);
            #pragma unroll
            for (int i = 0; i < 16; i += 2) {
                mn[0] = fminf(mn[0], fminf(c0[i], c0[i + 1]));
                mn[1] = fminf(mn[1], fminf(c1[i], c1[i + 1]));
                mn[2] = fminf(mn[2], fminf(c2[i], c2[i + 1]));
                mn[3] = fminf(mn[3], fminf(c3[i], c3[i + 1]));
            }
        }
        __syncthreads();
    }
    const int obase = dir * (BATCH * NPTS) + b * NPTS;
    #pragma unroll
    for (int nb = 0; nb < 4; ++nb) {
        const float o = __shfl_xor(mn[nb], 32, 64);
        const float m = fminf(mn[nb], o);
        if (ln < 32) {
            const unsigned u   = __float_as_uint(m);
            const unsigned key = (u >> 31) ? ~u : (u | 0x80000000u);
            atomicMin(&wskeys[obase + qbase + nb * 32 + ln], key);
        }
    }
}

__global__ __launch_bounds__(THREADS)
void chamfer_finish_kernel(const unsigned* __restrict__ ws,
                           float* __restrict__ out,
                           float inv_count)
{
    const int t = blockIdx.x * THREADS + threadIdx.x;
    const uint4 kk = ((const uint4*)ws)[t];
    float s = 0.0f;
    { const unsigned u = (kk.x >> 31) ? (kk.x ^ 0x80000000u) : ~kk.x; s += fmaxf(__uint_as_float(u), 0.0f); }
    { const unsigned u = (kk.y >> 31) ? (kk.y ^ 0x80000000u) : ~kk.y; s += fmaxf(__uint_as_float(u), 0.0f); }
    { const unsigned u = (kk.z >> 31) ? (kk.z ^ 0x80000000u) : ~kk.z; s += fmaxf(__uint_as_float(u), 0.0f); }
    { const unsigned u = (kk.w >> 31) ? (kk.w ^ 0x80000000u) : ~kk.w; s += fmaxf(__uint_as_float(u), 0.0f); }
    float v = s;
    #pragma unroll
    for (int off = 32; off > 0; off >>= 1)
        v += __shfl_down(v, off, 64);
    __shared__ float wsum[THREADS / 64];
    if ((threadIdx.x & 63) == 0) wsum[threadIdx.x >> 6] = v;
    __syncthreads();
    if (threadIdx.x == 0)
        atomicAdd(out, (wsum[0] + wsum[1] + wsum[2] + wsum[3]) * inv_count);
}

// ================= tier-3 fallback =================
__global__ __launch_bounds__(THREADS, 2)
void chamfer_fallback_kernel(const float* __restrict__ pred,
                             const float* __restrict__ target,
                             float* __restrict__ out,
                             float inv_count)
{
    __shared__ float4 lds[2048];
    const float* q  = (blockIdx.y == 0) ? pred   : target;
    const float* db = (blockIdx.y == 0) ? target : pred;
    const int b = blockIdx.x / (NPTS / THREADS);
    const int n = (blockIdx.x % (NPTS / THREADS)) * THREADS + threadIdx.x;
    const float* qp = q + ((size_t)b * NPTS + n) * 3;
    const float px = qp[0], py = qp[1], pz = qp[2];
    const float npx = -2.0f * px, npy = -2.0f * py, npz = -2.0f * pz;
    const float P = px * px + py * py + pz * pz;
    const float* dbB = db + (size_t)b * NPTS * 3;
    float m0 = INFINITY;
    for (int c0 = 0; c0 < NPTS; c0 += 2048) {
        for (int k = 0; k < 2048 / THREADS; ++k) {
            const int j = k * THREADS + threadIdx.x;
            const float* tp = dbB + (size_t)(c0 + j) * 3;
            const float tx = tp[0], ty = tp[1], tz = tp[2];
            lds[j] = make_float4(tx, ty, tz, tx * tx + ty * ty + tz * tz);
        }
        __syncthreads();
        for (int j = 0; j < 2048; ++j) {
            const float4 T = lds[j];
            m0 = fminf(m0, fmaf(npx, T.x, fmaf(npy, T.y, fmaf(npz, T.z, T.w))));
        }
        __syncthreads();
    }
    float v = fmaxf(P + m0, 0.0f);
    #pragma unroll
    for (int off = 32; off > 0; off >>= 1)
        v += __shfl_down(v, off, 64);
    __shared__ float wsum[THREADS / 64];
    if ((threadIdx.x & 63) == 0) wsum[threadIdx.x >> 6] = v;
    __syncthreads();
    if (threadIdx.x == 0)
        atomicAdd(out, (wsum[0] + wsum[1] + wsum[2] + wsum[3]) * inv_count);
}

extern "C" void kernel_launch(void* const* d_in, const int* in_sizes, int n_in,
                              void* d_out, int out_size, void* d_ws, size_t ws_size,
                              hipStream_t stream) {
    const float* pred   = (const float*)d_in[0];
    const float* target = (const float*)d_in[1];
    float* out = (float*)d_out;
    const float inv_count = 1.0f / (float)(BATCH * NPTS);

    if (ws_size >= WS1_BYTES) {
        uint4* enc  = (uint4*)d_ws;
        float* mins = (float*)((char*)d_ws + ENC_BYTES);
        hipMemsetAsync(out, 0, out_size * sizeof(float), stream);
        chamfer_encode_kernel<<<(2 * BATCH * NPTS) / THREADS, THREADS, 0, stream>>>(pred, target, enc);
        chamfer_mfma3_kernel<<<1024, THREADS, 0, stream>>>(pred, target, enc, mins);
        chamfer_finish3_kernel<<<ENTRIES / (THREADS * 8), THREADS, 0, stream>>>(mins, out, inv_count);
    } else if (ws_size >= WS_BYTES) {
        hipMemsetAsync(out, 0, out_size * sizeof(float), stream);
        unsigned* ws = (unsigned*)d_ws;
        hipMemsetAsync(ws, 0xFF, WS_BYTES, stream);
        chamfer_mfma_kernel<<<1024, THREADS, 0, stream>>>(pred, target, ws);
        chamfer_finish_kernel<<<ENTRIES / (THREADS * 4), THREADS, 0, stream>>>(ws, out, inv_count);
    } else {
        hipMemsetAsync(out, 0, out_size * sizeof(float), stream);
        dim3 grid(BATCH * (NPTS / THREADS), 2);
        chamfer_fallback_kernel<<<grid, THREADS, 0, stream>>>(pred, target, out, inv_count);
    }
}